// Round 10
// baseline (354.078 us; speedup 1.0000x reference)
//
#include <hip/hip_runtime.h>
#include <hip/hip_fp16.h>

// 2-branch PolyConv GNN + MLP head. float32, int32 indices.
// f_k = L^k h, L(f) = f - dinv*S(f*dinv). Filters = linear combos of f_0,f_1,f_2:
//   ortho: o0 = 3f0-3f1+0.75f2, o1 = 3f1-1.5f2, o2 = 0.75f2
//   sim:   all three = 4(f0+f1+f2)
// R17 vs R16 (2-node interleave was -2us vs R14; VALU 52->39 but time flat =>
// hop2 at compulsory-traffic floor ~3.7-4TB/s for random 128B gathers):
//  (1) hops reverted to R14's best-measured structure (1 node/wave, uniform
//      16/8 padded batches) keeping R16's 32-bit gather offsets ((d<<6)|lane).
//  (2) esrc stored as u16 (N=50000<65536; staged packing already assumed
//      16-bit ids): halves esrc fetch in both hops and place's scatter writes.
// hall slots (stride 384): ortho f0/f1/f2 -> 0/64/128, sim -> 192/256/320.
// dinv (2N f32) lives in logits region (overwritten by MLP last).
// d_ws: row_o[N+1] row_s[N+1] pend_o[N] pend_s[N] esrc_o/esrc_s (u16, padded)
//       bhist[128] brow[130] gcur[128] w1f[256*64 f32]
//       h16_o/h16_s/g16_o/g16_s[(N+1)*64 halves] (row N = zero row)
//       staged[E+Es] aliases h16 (consumed by place BEFORE in_gemm writes h16).

#define KB_BITS 10          // 1024 nodes per bucket
#define KMAX 64             // max buckets per graph (N <= 65535 for u16 esrc)
#define PCHUNK 4096
#define PVPT 16
#define PADMAX 7168         // max pad slots per bucket (1024 nodes * 7)

// Per-graph coarse-bucket histogram (both graphs, one launch).
__global__ __launch_bounds__(256) void bhist_kernel(
    const int* __restrict__ dst, const int* __restrict__ sim_dst,
    int* __restrict__ bhist, int E, int Es) {
    __shared__ int h[2 * KMAX];
    int tid = threadIdx.x;
    if (tid < 2 * KMAX) h[tid] = 0;
    __syncthreads();
    int total = E + Es;
    for (int e = blockIdx.x * 256 + tid; e < total; e += gridDim.x * 256) {
        if (e < E) atomicAdd(&h[dst[e] >> KB_BITS], 1);
        else       atomicAdd(&h[KMAX + (sim_dst[e - E] >> KB_BITS)], 1);
    }
    __syncthreads();
    if (tid < 2 * KMAX && h[tid]) atomicAdd(&bhist[tid], h[tid]);
}

// Bucket bases: brow[g][0..K] (exclusive prefix + total), gcur init = base.
__global__ __launch_bounds__(128) void bscan_kernel(
    const int* __restrict__ bhist, int* __restrict__ brow,
    int* __restrict__ gcur) {
    int g = threadIdx.x >> 6, lane = threadIdx.x & 63;
    int v = bhist[g * KMAX + lane];
    int inc = v;
    #pragma unroll
    for (int off = 1; off < 64; off <<= 1) {
        int u = __shfl_up(inc, off);
        if (lane >= off) inc += u;
    }
    int ex = inc - v;
    brow[g * (KMAX + 1) + lane] = ex;
    if (lane == 63) brow[g * (KMAX + 1) + KMAX] = inc;
    gcur[g * KMAX + lane] = ex;
}

// LDS radix partition: per 4096-edge block, sort by bucket in LDS, reserve one
// contiguous global run per bucket, stream out coalesced.
__global__ __launch_bounds__(256) void partition_kernel(
    const int* __restrict__ src, const int* __restrict__ dst,
    const int* __restrict__ sim_src, const int* __restrict__ sim_dst,
    int* __restrict__ gcur, unsigned* __restrict__ staged,
    int E, int Es, int nbo) {
    int b = blockIdx.x;
    const int* S; const int* D; int Eg; int goff; unsigned* stg;
    if (b < nbo) { S = src; D = dst; Eg = E; goff = 0; stg = staged; }
    else { b -= nbo; S = sim_src; D = sim_dst; Eg = Es; goff = KMAX; stg = staged + E; }
    int e0 = b * PCHUNK;
    int cnt_blk = Eg - e0; if (cnt_blk > PCHUNK) cnt_blk = PCHUNK;
    __shared__ int hist[KMAX], basep[KMAX], cur[KMAX], gbase[KMAX];
    __shared__ unsigned srt[PCHUNK];
    int tid = threadIdx.x;
    if (tid < KMAX) hist[tid] = 0;
    __syncthreads();
    unsigned full[PVPT];
    #pragma unroll
    for (int i = 0; i < PVPT; ++i) {
        int idx = i * 256 + tid;
        if (idx < cnt_blk) {
            int e = e0 + idx;
            int d = D[e];
            unsigned bk = (unsigned)d >> KB_BITS;
            full[i] = (bk << 26) | ((unsigned)S[e] << KB_BITS) |
                      (unsigned)(d & ((1 << KB_BITS) - 1));
            atomicAdd(&hist[bk], 1);
        } else full[i] = 0xFFFFFFFFu;
    }
    __syncthreads();
    if (tid < 64) {
        int v = hist[tid];
        int inc = v;
        #pragma unroll
        for (int off = 1; off < 64; off <<= 1) {
            int u = __shfl_up(inc, off);
            if (tid >= off) inc += u;
        }
        int ex = inc - v;
        basep[tid] = ex;
        cur[tid] = ex;
        gbase[tid] = v ? atomicAdd(&gcur[goff + tid], v) : 0;
    }
    __syncthreads();
    #pragma unroll
    for (int i = 0; i < PVPT; ++i) {
        unsigned f = full[i];
        if (f != 0xFFFFFFFFu) {
            unsigned bk = f >> 26;
            int slot = atomicAdd(&cur[bk], 1);
            srt[slot] = f;
        }
    }
    __syncthreads();
    for (int slot = tid; slot < cnt_blk; slot += 256) {
        unsigned f = srt[slot];
        unsigned bk = f >> 26;
        int gpos = gbase[bk] + (slot - basep[bk]);
        stg[gpos] = f & 0x3FFFFFFu;      // (src<<10)|dlow
    }
}

// One block per bucket: per-node counts -> row/pend/dinv, pad-fill (src=N),
// then scatter u16 esrc inside the bucket's private padded window.
__global__ __launch_bounds__(512) void place_kernel(
    const unsigned* __restrict__ staged, const int* __restrict__ brow,
    int* __restrict__ row_o, int* __restrict__ row_s,
    int* __restrict__ pend_o, int* __restrict__ pend_s,
    unsigned short* __restrict__ esrc_o, unsigned short* __restrict__ esrc_s,
    float* __restrict__ dinv, int N, int K, int E, int pad) {
    int b = blockIdx.x;
    const unsigned* stg; const int* br; int* row; int* pend;
    unsigned short* esrc; float* dv;
    if (b < K) { stg = staged; br = brow; row = row_o; pend = pend_o; esrc = esrc_o; dv = dinv; }
    else { b -= K; stg = staged + E; br = brow + (KMAX + 1); row = row_s; pend = pend_s; esrc = esrc_s; dv = dinv + N; }
    int node0 = b << KB_BITS;
    int nn = N - node0; if (nn > (1 << KB_BITS)) nn = (1 << KB_BITS);
    int seg0 = br[b], seg1 = br[b + 1];
    int base = pad ? (seg0 + b * PADMAX) : seg0;
    __shared__ int ncnt[1 << KB_BITS];
    __shared__ int wsum[8];
    int tid = threadIdx.x;
    for (int i = tid; i < (1 << KB_BITS); i += 512) ncnt[i] = 0;
    __syncthreads();
    for (int j = seg0 + tid; j < seg1; j += 512)
        atomicAdd(&ncnt[stg[j] & ((1 << KB_BITS) - 1)], 1);
    __syncthreads();
    int i0 = tid * 2;
    int v0 = ncnt[i0], v1 = ncnt[i0 + 1];
    int p0 = pad ? ((v0 + 7) & ~7) : v0;
    int p1 = pad ? ((v1 + 7) & ~7) : v1;
    int s = p0 + p1;
    int inc = s;
    #pragma unroll
    for (int off = 1; off < 64; off <<= 1) {
        int u = __shfl_up(inc, off);
        if ((tid & 63) >= off) inc += u;
    }
    if ((tid & 63) == 63) wsum[tid >> 6] = inc;
    __syncthreads();
    int wo = 0;
    for (int w = 0; w < (tid >> 6); ++w) wo += wsum[w];
    int ex = base + wo + inc - s;
    if (i0 < nn) {
        row[node0 + i0] = ex;
        pend[node0 + i0] = ex + p0;
        dv[node0 + i0] = rsqrtf((float)(v0 > 1 ? v0 : 1));
        for (int q = ex + v0; q < ex + p0; ++q) esrc[q] = (unsigned short)N;
    }
    if (i0 + 1 < nn) {
        int ex2 = ex + p0;
        row[node0 + i0 + 1] = ex2;
        pend[node0 + i0 + 1] = ex2 + p1;
        dv[node0 + i0 + 1] = rsqrtf((float)(v1 > 1 ? v1 : 1));
        for (int q = ex2 + v1; q < ex2 + p1; ++q) esrc[q] = (unsigned short)N;
    }
    if (!pad && b == K - 1 && tid == 0) row[N] = br[K];
    __syncthreads();
    ncnt[i0] = ex;
    ncnt[i0 + 1] = ex + p0;
    __syncthreads();
    for (int j = seg0 + tid; j < seg1; j += 512) {
        unsigned f = stg[j];
        int pos = atomicAdd(&ncnt[f & ((1 << KB_BITS) - 1)], 1);
        esrc[pos] = (unsigned short)(f >> KB_BITS);
    }
}

// Fold Wm1 (384x64) -> w1f (256x64): rows 192..255 = sum of the 3 sim blocks.
// Block 0 also zeroes bhist (replaces the memset dispatch).
__global__ __launch_bounds__(256) void fold_kernel(
    const float* __restrict__ Wm1, float* __restrict__ w1f,
    int* __restrict__ bhist) {
    int i = blockIdx.x * 256 + threadIdx.x;
    if (blockIdx.x == 0 && threadIdx.x < 2 * KMAX) bhist[threadIdx.x] = 0;
    if (i >= 256 * 64) return;
    int k = i >> 6, j = i & 63;
    float v = Wm1[k * 64 + j];
    if (k >= 192) v += Wm1[(k + 64) * 64 + j] + Wm1[(k + 128) * 64 + j];
    w1f[i] = v;
}

// Both input GEMMs in one launch: block < nbh -> ortho, else sim.
// f16path: writes ONLY h16 = relu*dinv (premul); also zeroes the pad row N.
__global__ __launch_bounds__(256) void in_gemm2_kernel(
    const float* __restrict__ x, const float* __restrict__ sim_x,
    const float* __restrict__ W1_o, const float* __restrict__ b1_o,
    const float* __restrict__ W1_s, const float* __restrict__ b1_s,
    float* __restrict__ hall, __half* __restrict__ h16_o, __half* __restrict__ h16_s,
    __half* __restrict__ g16_o, __half* __restrict__ g16_s,
    const float* __restrict__ dinv, int n, int nbh, int f16path, int pad) {
    int bb = blockIdx.x;
    const float* xin; const float* W; const float* b; __half* h16;
    const float* dinvv; int off;
    if (bb < nbh) { xin = x; W = W1_o; b = b1_o; h16 = h16_o; dinvv = dinv; off = 0; }
    else { bb -= nbh; xin = sim_x; W = W1_s; b = b1_s; h16 = h16_s; dinvv = dinv + n; off = 192; }
    if (pad && threadIdx.x < 64) {       // zero rows for padded gathers
        if (blockIdx.x == 0) {
            h16_o[(long)n * 64 + threadIdx.x] = __float2half_rn(0.f);
            g16_o[(long)n * 64 + threadIdx.x] = __float2half_rn(0.f);
        } else if (blockIdx.x == nbh) {
            h16_s[(long)n * 64 + threadIdx.x] = __float2half_rn(0.f);
            g16_s[(long)n * 64 + threadIdx.x] = __float2half_rn(0.f);
        }
    }
    __shared__ float xs[64][132];
    __shared__ float Wf[128][68];
    int tid = threadIdx.x;
    int node0 = bb * 64;
    const float4* wsrc = (const float4*)W;
    for (int i = tid; i < 2048; i += 256)
        *(float4*)&Wf[i >> 4][(i & 15) * 4] = wsrc[i];
    const float4* xsrc = (const float4*)xin;
    for (int i = tid; i < 2048; i += 256) {
        int nl = i >> 5, c = i & 31;
        int node = node0 + nl;
        float4 v = make_float4(0.f, 0.f, 0.f, 0.f);
        if (node < n) v = xsrc[(long)node * 32 + c];
        *(float4*)&xs[nl][c * 4] = v;
    }
    __syncthreads();
    int tx = tid & 15, ty = tid >> 4;
    float acc[4][4] = {};
    #pragma unroll 2
    for (int k = 0; k < 128; k += 4) {
        float4 a[4], bbv[4];
        #pragma unroll
        for (int i = 0; i < 4; ++i) a[i] = *(const float4*)&xs[ty * 4 + i][k];
        #pragma unroll
        for (int j = 0; j < 4; ++j) bbv[j] = *(const float4*)&Wf[k + j][tx * 4];
        #pragma unroll
        for (int i = 0; i < 4; ++i) {
            acc[i][0] = fmaf(a[i].x, bbv[0].x, acc[i][0]);
            acc[i][1] = fmaf(a[i].x, bbv[0].y, acc[i][1]);
            acc[i][2] = fmaf(a[i].x, bbv[0].z, acc[i][2]);
            acc[i][3] = fmaf(a[i].x, bbv[0].w, acc[i][3]);
            acc[i][0] = fmaf(a[i].y, bbv[1].x, acc[i][0]);
            acc[i][1] = fmaf(a[i].y, bbv[1].y, acc[i][1]);
            acc[i][2] = fmaf(a[i].y, bbv[1].z, acc[i][2]);
            acc[i][3] = fmaf(a[i].y, bbv[1].w, acc[i][3]);
            acc[i][0] = fmaf(a[i].z, bbv[2].x, acc[i][0]);
            acc[i][1] = fmaf(a[i].z, bbv[2].y, acc[i][1]);
            acc[i][2] = fmaf(a[i].z, bbv[2].z, acc[i][2]);
            acc[i][3] = fmaf(a[i].z, bbv[2].w, acc[i][3]);
            acc[i][0] = fmaf(a[i].w, bbv[3].x, acc[i][0]);
            acc[i][1] = fmaf(a[i].w, bbv[3].y, acc[i][1]);
            acc[i][2] = fmaf(a[i].w, bbv[3].z, acc[i][2]);
            acc[i][3] = fmaf(a[i].w, bbv[3].w, acc[i][3]);
        }
    }
    float4 bias = *(const float4*)&b[tx * 4];
    #pragma unroll
    for (int i = 0; i < 4; ++i) {
        int node = node0 + ty * 4 + i;
        if (node >= n) break;
        float4 r;
        r.x = fmaxf(acc[i][0] + bias.x, 0.0f);
        r.y = fmaxf(acc[i][1] + bias.y, 0.0f);
        r.z = fmaxf(acc[i][2] + bias.z, 0.0f);
        r.w = fmaxf(acc[i][3] + bias.w, 0.0f);
        if (f16path) {
            float dvn = dinvv[node];
            __half hh[4];
            hh[0] = __float2half_rn(r.x * dvn);
            hh[1] = __float2half_rn(r.y * dvn);
            hh[2] = __float2half_rn(r.z * dvn);
            hh[3] = __float2half_rn(r.w * dvn);
            *(float2*)&h16[(long)node * 64 + tx * 4] = *(float2*)hh;
        } else {
            *(float4*)&hall[(long)node * 384 + off + tx * 4] = r;
        }
    }
}

// Hop 1 (R14 structure): 1 node/wave, uniform 16/8 batches, 32-bit offsets,
// u16 esrc. g16 = h16_own - acc*dd^2 (= f1*dinv).
__global__ __launch_bounds__(256) void hop1_kernel(
    const int* __restrict__ row_o, const int* __restrict__ pend_o,
    const unsigned short* __restrict__ esrc_o, const float* __restrict__ dinv_o,
    const int* __restrict__ row_s, const int* __restrict__ pend_s,
    const unsigned short* __restrict__ esrc_s, const float* __restrict__ dinv_s,
    const __half* __restrict__ h16_o, const __half* __restrict__ h16_s,
    __half* __restrict__ g16_o, __half* __restrict__ g16_s,
    int n, int nb) {
    int b = blockIdx.x;
    const int* row; const int* pend; const unsigned short* esrc;
    const float* dinv; const __half* h16; __half* g16;
    if (b < nb) { row = row_o; pend = pend_o; esrc = esrc_o; dinv = dinv_o; h16 = h16_o; g16 = g16_o; }
    else { b -= nb; row = row_s; pend = pend_s; esrc = esrc_s; dinv = dinv_s; h16 = h16_s; g16 = g16_s; }
    int d = b * 4 + (threadIdx.x >> 6);
    if (d >= n) return;
    int lane = threadIdx.x & 63;
    int p = row[d], end = pend[d];
    float dd = dinv[d];
    float h16v = __half2float(h16[((unsigned)d << 6) | lane]);
    float a0 = 0.f, a1 = 0.f, a2 = 0.f, a3 = 0.f;
    for (; p + 16 <= end; p += 16) {
        unsigned ss[16];
        #pragma unroll
        for (int i = 0; i < 16; ++i) ss[i] = esrc[p + i];
        #pragma unroll
        for (int i = 0; i < 16; i += 4) {
            a0 += __half2float(h16[(ss[i] << 6) | lane]);
            a1 += __half2float(h16[(ss[i + 1] << 6) | lane]);
            a2 += __half2float(h16[(ss[i + 2] << 6) | lane]);
            a3 += __half2float(h16[(ss[i + 3] << 6) | lane]);
        }
    }
    if (p + 8 <= end) {
        unsigned ss[8];
        #pragma unroll
        for (int i = 0; i < 8; ++i) ss[i] = esrc[p + i];
        #pragma unroll
        for (int i = 0; i < 8; i += 4) {
            a0 += __half2float(h16[(ss[i] << 6) | lane]);
            a1 += __half2float(h16[(ss[i + 1] << 6) | lane]);
            a2 += __half2float(h16[(ss[i + 2] << 6) | lane]);
            a3 += __half2float(h16[(ss[i + 3] << 6) | lane]);
        }
        p += 8;
    }
    for (; p + 4 <= end; p += 4) {       // tier-B only
        unsigned s0 = esrc[p], s1 = esrc[p + 1], s2 = esrc[p + 2], s3 = esrc[p + 3];
        a0 += __half2float(h16[(s0 << 6) | lane]);
        a1 += __half2float(h16[(s1 << 6) | lane]);
        a2 += __half2float(h16[(s2 << 6) | lane]);
        a3 += __half2float(h16[(s3 << 6) | lane]);
    }
    for (; p < end; ++p)
        a0 += __half2float(h16[((unsigned)esrc[p] << 6) | lane]);
    float acc = (a0 + a1) + (a2 + a3);
    g16[((unsigned)d << 6) | lane] = __float2half_rn(h16v - acc * dd * dd);
}

// Hop 2 + theta-combine (R14 structure): 1 node/wave, uniform 16/8 batches,
// 32-bit offsets, u16 esrc. Reconstructs f0,f1 via sq = 1/dd.
__global__ __launch_bounds__(256) void hop2_kernel(
    const int* __restrict__ row_o, const int* __restrict__ pend_o,
    const unsigned short* __restrict__ esrc_o, const float* __restrict__ dinv_o,
    const int* __restrict__ row_s, const int* __restrict__ pend_s,
    const unsigned short* __restrict__ esrc_s, const float* __restrict__ dinv_s,
    const __half* __restrict__ h16_o, const __half* __restrict__ h16_s,
    const __half* __restrict__ g16_o, const __half* __restrict__ g16_s,
    float* __restrict__ hall, int n, int nb) {
    int b = blockIdx.x;
    int g = (b < nb) ? 0 : 1;
    const int* row; const int* pend; const unsigned short* esrc;
    const float* dinv; const __half* h16; const __half* g16;
    if (g == 0) { row = row_o; pend = pend_o; esrc = esrc_o; dinv = dinv_o; h16 = h16_o; g16 = g16_o; }
    else { b -= nb; row = row_s; pend = pend_s; esrc = esrc_s; dinv = dinv_s; h16 = h16_s; g16 = g16_s; }
    int d = b * 4 + (threadIdx.x >> 6);
    if (d >= n) return;
    int lane = threadIdx.x & 63;
    int p = row[d], end = pend[d];
    float dd = dinv[d];
    float sq = 1.0f / dd;                 // = sqrt(clamped degree)
    float f0 = __half2float(h16[((unsigned)d << 6) | lane]) * sq;
    float f1 = __half2float(g16[((unsigned)d << 6) | lane]) * sq;
    float a0 = 0.f, a1 = 0.f, a2 = 0.f, a3 = 0.f;
    for (; p + 16 <= end; p += 16) {
        unsigned ss[16];
        #pragma unroll
        for (int i = 0; i < 16; ++i) ss[i] = esrc[p + i];
        #pragma unroll
        for (int i = 0; i < 16; i += 4) {
            a0 += __half2float(g16[(ss[i] << 6) | lane]);
            a1 += __half2float(g16[(ss[i + 1] << 6) | lane]);
            a2 += __half2float(g16[(ss[i + 2] << 6) | lane]);
            a3 += __half2float(g16[(ss[i + 3] << 6) | lane]);
        }
    }
    if (p + 8 <= end) {
        unsigned ss[8];
        #pragma unroll
        for (int i = 0; i < 8; ++i) ss[i] = esrc[p + i];
        #pragma unroll
        for (int i = 0; i < 8; i += 4) {
            a0 += __half2float(g16[(ss[i] << 6) | lane]);
            a1 += __half2float(g16[(ss[i + 1] << 6) | lane]);
            a2 += __half2float(g16[(ss[i + 2] << 6) | lane]);
            a3 += __half2float(g16[(ss[i + 3] << 6) | lane]);
        }
        p += 8;
    }
    for (; p + 4 <= end; p += 4) {       // tier-B only
        unsigned s0 = esrc[p], s1 = esrc[p + 1], s2 = esrc[p + 2], s3 = esrc[p + 3];
        a0 += __half2float(g16[(s0 << 6) | lane]);
        a1 += __half2float(g16[(s1 << 6) | lane]);
        a2 += __half2float(g16[(s2 << 6) | lane]);
        a3 += __half2float(g16[(s3 << 6) | lane]);
    }
    for (; p < end; ++p)
        a0 += __half2float(g16[((unsigned)esrc[p] << 6) | lane]);
    float acc = (a0 + a1) + (a2 + a3);
    float f2 = f1 - acc * dd;
    long ob = (long)d * 384 + lane;
    if (g == 0) {
        hall[ob]       = 3.0f * f0 - 3.0f * f1 + 0.75f * f2;
        hall[ob + 64]  = 3.0f * f1 - 1.5f * f2;
        hall[ob + 128] = 0.75f * f2;
    } else {
        float ss = 4.0f * (f0 + f1 + f2);
        hall[ob + 192] = ss; hall[ob + 256] = ss; hall[ob + 320] = ss;
    }
}

// ---------- fallback path (ws too small for fp16 shadows) ----------
__global__ __launch_bounds__(256) void gather2_kernel(
    const int* __restrict__ row_o, const unsigned short* __restrict__ esrc_o,
    const float* __restrict__ dinv_o,
    const int* __restrict__ row_s, const unsigned short* __restrict__ esrc_s,
    const float* __restrict__ dinv_s,
    float* __restrict__ hall, int in_off_o, int in_off_s, int n, int nb) {
    int b = blockIdx.x;
    const int* row; const unsigned short* esrc; const float* dinv; int in_off;
    if (b < nb) { row = row_o; esrc = esrc_o; dinv = dinv_o; in_off = in_off_o; }
    else { b -= nb; row = row_s; esrc = esrc_s; dinv = dinv_s; in_off = in_off_s; }
    int d = b * 4 + (threadIdx.x >> 6);
    if (d >= n) return;
    int lane = threadIdx.x & 63;
    int p = row[d], end = row[d + 1];
    const float* fin = hall + in_off;
    float a0 = 0.f, a1 = 0.f, a2 = 0.f, a3 = 0.f;
    for (; p + 4 <= end; p += 4) {
        int s0 = esrc[p], s1 = esrc[p + 1], s2 = esrc[p + 2], s3 = esrc[p + 3];
        a0 = fmaf(fin[(long)s0 * 384 + lane], dinv[s0], a0);
        a1 = fmaf(fin[(long)s1 * 384 + lane], dinv[s1], a1);
        a2 = fmaf(fin[(long)s2 * 384 + lane], dinv[s2], a2);
        a3 = fmaf(fin[(long)s3 * 384 + lane], dinv[s3], a3);
    }
    for (; p < end; ++p) {
        int s = esrc[p];
        a0 = fmaf(fin[(long)s * 384 + lane], dinv[s], a0);
    }
    float acc = (a0 + a1) + (a2 + a3);
    long ob = (long)d * 384 + lane;
    hall[ob + in_off + 64] = fin[ob] - acc * dinv[d];
}

__global__ __launch_bounds__(256) void combine_kernel(float* __restrict__ h, int nf) {
    int i = blockIdx.x * 256 + threadIdx.x;
    if (i >= nf) return;
    long ob = (long)(i >> 6) * 384 + (i & 63);
    float f0v = h[ob], f1v = h[ob + 64], f2v = h[ob + 128];
    h[ob]       = 3.0f * f0v - 3.0f * f1v + 0.75f * f2v;
    h[ob + 64]  = 3.0f * f1v - 1.5f * f2v;
    h[ob + 128] = 0.75f * f2v;
    float ss = 4.0f * (h[ob + 192] + h[ob + 256] + h[ob + 320]);
    h[ob + 192] = ss; h[ob + 256] = ss; h[ob + 320] = ss;
}
// -------------------------------------------------------------------

// logits = relu(h_all @ Wm1f + bm1) @ Wm2 + bm2. K=256 (sim slots folded).
__global__ __launch_bounds__(256) void mlp_kernel(
    const float* __restrict__ hall, const float* __restrict__ w1f,
    const float* __restrict__ bm1, const float* __restrict__ Wm2,
    const float* __restrict__ bm2, float* __restrict__ logits, int n) {
    __shared__ float xs[64][132];
    __shared__ float Wf[128][68];
    int tid = threadIdx.x;
    int node0 = blockIdx.x * 64;
    int tx = tid & 15, ty = tid >> 4;
    float acc[4][4] = {};
    const float4* wsrc = (const float4*)w1f;
    const float4* hsrc = (const float4*)hall;
    for (int c = 0; c < 2; ++c) {
        __syncthreads();
        for (int i = tid; i < 2048; i += 256)
            *(float4*)&Wf[i >> 4][(i & 15) * 4] = wsrc[c * 2048 + i];
        for (int i = tid; i < 2048; i += 256) {
            int nl = i >> 5, cc = i & 31;
            int node = node0 + nl;
            float4 v = make_float4(0.f, 0.f, 0.f, 0.f);
            if (node < n) v = hsrc[(long)node * 96 + c * 32 + cc];
            *(float4*)&xs[nl][cc * 4] = v;
        }
        __syncthreads();
        #pragma unroll 2
        for (int k = 0; k < 128; k += 4) {
            float4 a[4], bb[4];
            #pragma unroll
            for (int i = 0; i < 4; ++i) a[i] = *(const float4*)&xs[ty * 4 + i][k];
            #pragma unroll
            for (int j = 0; j < 4; ++j) bb[j] = *(const float4*)&Wf[k + j][tx * 4];
            #pragma unroll
            for (int i = 0; i < 4; ++i) {
                acc[i][0] = fmaf(a[i].x, bb[0].x, acc[i][0]);
                acc[i][1] = fmaf(a[i].x, bb[0].y, acc[i][1]);
                acc[i][2] = fmaf(a[i].x, bb[0].z, acc[i][2]);
                acc[i][3] = fmaf(a[i].x, bb[0].w, acc[i][3]);
                acc[i][0] = fmaf(a[i].y, bb[1].x, acc[i][0]);
                acc[i][1] = fmaf(a[i].y, bb[1].y, acc[i][1]);
                acc[i][2] = fmaf(a[i].y, bb[1].z, acc[i][2]);
                acc[i][3] = fmaf(a[i].y, bb[1].w, acc[i][3]);
                acc[i][0] = fmaf(a[i].z, bb[2].x, acc[i][0]);
                acc[i][1] = fmaf(a[i].z, bb[2].y, acc[i][1]);
                acc[i][2] = fmaf(a[i].z, bb[2].z, acc[i][2]);
                acc[i][3] = fmaf(a[i].z, bb[2].w, acc[i][3]);
                acc[i][0] = fmaf(a[i].w, bb[3].x, acc[i][0]);
                acc[i][1] = fmaf(a[i].w, bb[3].y, acc[i][1]);
                acc[i][2] = fmaf(a[i].w, bb[3].z, acc[i][2]);
                acc[i][3] = fmaf(a[i].w, bb[3].w, acc[i][3]);
            }
        }
    }
    __syncthreads();
    float4 bias = *(const float4*)&bm1[tx * 4];
    #pragma unroll
    for (int i = 0; i < 4; ++i) {
        xs[ty * 4 + i][tx * 4 + 0] = fmaxf(acc[i][0] + bias.x, 0.0f);
        xs[ty * 4 + i][tx * 4 + 1] = fmaxf(acc[i][1] + bias.y, 0.0f);
        xs[ty * 4 + i][tx * 4 + 2] = fmaxf(acc[i][2] + bias.z, 0.0f);
        xs[ty * 4 + i][tx * 4 + 3] = fmaxf(acc[i][3] + bias.w, 0.0f);
    }
    __syncthreads();
    if (tid < 128) {
        int nl = tid >> 1, o = tid & 1;
        int node = node0 + nl;
        if (node < n) {
            float p = bm2[o];
            #pragma unroll 8
            for (int k = 0; k < 64; ++k) p = fmaf(xs[nl][k], Wm2[k * 2 + o], p);
            logits[(long)node * 2 + o] = p;
        }
    }
}

extern "C" void kernel_launch(void* const* d_in, const int* in_sizes, int n_in,
                              void* d_out, int out_size, void* d_ws, size_t ws_size,
                              hipStream_t stream) {
    const float* x     = (const float*)d_in[0];
    const float* sim_x = (const float*)d_in[1];
    const int* src     = (const int*)d_in[2];
    const int* dst     = (const int*)d_in[3];
    const int* sim_src = (const int*)d_in[4];
    const int* sim_dst = (const int*)d_in[5];
    const float* W1_o = (const float*)d_in[6];
    const float* b1_o = (const float*)d_in[7];
    const float* W1_s = (const float*)d_in[8];
    const float* b1_s = (const float*)d_in[9];
    const float* Wm1  = (const float*)d_in[10];
    const float* bm1  = (const float*)d_in[11];
    const float* Wm2  = (const float*)d_in[12];
    const float* bm2  = (const float*)d_in[13];

    const int N  = in_sizes[0] / 128;  // 50000 (must be <= 65535 for u16 path)
    const int E  = in_sizes[2];        // 800000
    const int Es = in_sizes[4];
    const int NF = N * 64;
    const int K  = (N + (1 << KB_BITS) - 1) >> KB_BITS;  // 1024-node buckets

    float* hall = (float*)d_out;                 // N x 384
    float* lgt  = hall + (long)N * 384;          // N x 2
    float* dinv = lgt;                           // [dinv_o N | dinv_s N] until MLP
    float* dinv_o = dinv;
    float* dinv_s = dinv + N;

    // ---- workspace layout (padded tier A; tier B unpadded; u16 esrc) ----
    int* row_o  = (int*)d_ws;            // N+1
    int* row_s  = row_o + (N + 1);       // N+1
    int* pend_o = row_s + (N + 1);       // N
    int* pend_s = pend_o + N;            // N
    unsigned short* esrc_o = (unsigned short*)(pend_s + N);
    long esz_pad   = ((long)E + (long)K * PADMAX + 1) & ~1L;   // u16 count, 4B-aligned
    long esz_pad_s = ((long)Es + (long)K * PADMAX + 1) & ~1L;
    long esz_b     = ((long)E + 1) & ~1L;
    long esz_b_s   = ((long)Es + 1) & ~1L;

    // Tier A pointers:
    unsigned short* esrc_sA = esrc_o + esz_pad;
    int* bhistA = (int*)(esrc_sA + esz_pad_s);
    // Tier B pointers:
    unsigned short* esrc_sB = esrc_o + esz_b;
    int* bhistB = (int*)(esrc_sB + esz_b_s);

    auto layout_tail = [&](int* bh) -> char* {
        int* br = bh + 2 * KMAX;
        int* gc = br + 2 * (KMAX + 1);
        float* wf = (float*)(gc + 2 * KMAX);
        __half* h = (__half*)(wf + 256 * 64);
        return (char*)(h + 4 * (long)(N + 1) * 64);
    };
    bool u16ok = N <= 65535;
    bool padA = u16ok && (size_t)(layout_tail(bhistA) - (char*)d_ws) <= ws_size;
    unsigned short* esrc_s = padA ? esrc_sA : esrc_sB;
    int* bhist  = padA ? bhistA : bhistB;
    int* brow   = bhist + 2 * KMAX;
    int* gcur   = brow + 2 * (KMAX + 1);
    float* w1f  = (float*)(gcur + 2 * KMAX);
    __half* h16_o = (__half*)(w1f + 256 * 64);   // (N+1)*64 halves each
    __half* h16_s = h16_o + (long)(N + 1) * 64;
    __half* g16_o = h16_s + (long)(N + 1) * 64;
    __half* g16_s = g16_o + (long)(N + 1) * 64;
    bool f16path = u16ok && (padA ||
        ((size_t)(layout_tail(bhistB) - (char*)d_ws) <= ws_size));
    int pad = padA ? 1 : 0;
    // staged[E+Es] aliases h16 region: consumed by place BEFORE in_gemm writes h16.
    unsigned* staged = (unsigned*)h16_o;
    const int* pend_o_use = pad ? pend_o : (row_o + 1);
    const int* pend_s_use = pad ? pend_s : (row_s + 1);

    int nb4  = (N + 3) / 4;
    int nb64 = (N + 63) / 64;
    int nfb  = (NF + 255) / 256;
    int nbo  = (E + PCHUNK - 1) / PCHUNK;
    int nbs  = (Es + PCHUNK - 1) / PCHUNK;

    // ---- CSR build: fold(+bhist zero) -> hist -> bases -> partition -> place ----
    fold_kernel<<<64, 256, 0, stream>>>(Wm1, w1f, bhist);
    bhist_kernel<<<256, 256, 0, stream>>>(dst, sim_dst, bhist, E, Es);
    bscan_kernel<<<1, 128, 0, stream>>>(bhist, brow, gcur);
    partition_kernel<<<nbo + nbs, 256, 0, stream>>>(src, dst, sim_src, sim_dst,
                                                    gcur, staged, E, Es, nbo);
    place_kernel<<<2 * K, 512, 0, stream>>>(staged, brow, row_o, row_s,
                                            pend_o, pend_s, esrc_o, esrc_s,
                                            dinv, N, K, E, pad);

    // ---- input GEMMs (one launch, both graphs; zeroes pad rows) ----
    in_gemm2_kernel<<<2 * nb64, 256, 0, stream>>>(x, sim_x, W1_o, b1_o, W1_s, b1_s,
                                                  hall, h16_o, h16_s, g16_o, g16_s,
                                                  dinv, N, nb64, f16path ? 1 : 0, pad);

    if (f16path) {
        hop1_kernel<<<2 * nb4, 256, 0, stream>>>(row_o, pend_o_use, esrc_o, dinv_o,
                                                 row_s, pend_s_use, esrc_s, dinv_s,
                                                 h16_o, h16_s, g16_o, g16_s, N, nb4);
        hop2_kernel<<<2 * nb4, 256, 0, stream>>>(row_o, pend_o_use, esrc_o, dinv_o,
                                                 row_s, pend_s_use, esrc_s, dinv_s,
                                                 h16_o, h16_s, g16_o, g16_s,
                                                 hall, N, nb4);
    } else {
        gather2_kernel<<<2 * nb4, 256, 0, stream>>>(row_o, esrc_o, dinv_o,
                                                    row_s, esrc_s, dinv_s,
                                                    hall, 0, 192, N, nb4);
        gather2_kernel<<<2 * nb4, 256, 0, stream>>>(row_o, esrc_o, dinv_o,
                                                    row_s, esrc_s, dinv_s,
                                                    hall, 64, 256, N, nb4);
        combine_kernel<<<nfb, 256, 0, stream>>>(hall, NF);
    }

    // ---- MLP head (folded K=256; overwrites dinv stash with logits) ----
    mlp_kernel<<<nb64, 256, 0, stream>>>(hall, w1f, bm1, Wm2, bm2, lgt, N);
}

// Round 11
// 351.511 us; speedup vs baseline: 1.0073x; 1.0073x over previous
//
#include <hip/hip_runtime.h>
#include <hip/hip_fp16.h>
#include <hip/hip_fp8.h>

// 2-branch PolyConv GNN + MLP head. float32, int32 indices.
// f_k = L^k h, L(f) = f - dinv*S(f*dinv). Filters = linear combos of f_0,f_1,f_2:
//   ortho: o0 = 3f0-3f1+0.75f2, o1 = 3f1-1.5f2, o2 = 0.75f2
//   sim:   all three = 4(f0+f1+f2)
// R18 vs R17 (3-round plateau at ~353; hop2 pinned at 54us / 3.9TB/s with
// FETCH = 8xXCD gather-set fill + own rows => gather miss path is the wall):
//  fp8 e4m3 shadows for the GATHERED operand only (h8 = h*dinv, g8 = f1*dinv);
//  own-row f0/f1 reconstruction stays fp16 (h16/g16), so fp8 error enters only
//  via the neighbor sum. Gather row 128->64B (1 L2 line), per-graph gather set
//  6.4->3.2MB (fill 102->51MB). Tiers: A2 pad+fp8 -> A pad+fp16 -> B -> C.
// hall slots (stride 384): ortho f0/f1/f2 -> 0/64/128, sim -> 192/256/320.
// dinv (2N f32) lives in logits region (overwritten by MLP last).
// d_ws: row_o[N+1] row_s[N+1] pend_o[N] pend_s[N] esrc_o/esrc_s (u16, padded)
//       bhist[128] brow[130] gcur[128] w1f[256*64 f32]
//       h16/g16[(N+1)*64 halves x4] h8/g8[(N+1)*64 bytes x4] (row N = zero)
//       staged[E+Es] aliases h16 (consumed by place BEFORE in_gemm writes h16).

#define KB_BITS 10          // 1024 nodes per bucket
#define KMAX 64             // max buckets per graph (N <= 65535 for u16 esrc)
#define PCHUNK 4096
#define PVPT 16
#define PADMAX 7168         // max pad slots per bucket (1024 nodes * 7)

__device__ __forceinline__ float cv8(unsigned char b) {
    __hip_fp8_e4m3 v; v.__x = b; return (float)v;
}
__device__ __forceinline__ unsigned char to8(float f) {
    __hip_fp8_e4m3 v(f); return v.__x;
}

// Per-graph coarse-bucket histogram (both graphs, one launch).
__global__ __launch_bounds__(256) void bhist_kernel(
    const int* __restrict__ dst, const int* __restrict__ sim_dst,
    int* __restrict__ bhist, int E, int Es) {
    __shared__ int h[2 * KMAX];
    int tid = threadIdx.x;
    if (tid < 2 * KMAX) h[tid] = 0;
    __syncthreads();
    int total = E + Es;
    for (int e = blockIdx.x * 256 + tid; e < total; e += gridDim.x * 256) {
        if (e < E) atomicAdd(&h[dst[e] >> KB_BITS], 1);
        else       atomicAdd(&h[KMAX + (sim_dst[e - E] >> KB_BITS)], 1);
    }
    __syncthreads();
    if (tid < 2 * KMAX && h[tid]) atomicAdd(&bhist[tid], h[tid]);
}

// Bucket bases: brow[g][0..K] (exclusive prefix + total), gcur init = base.
__global__ __launch_bounds__(128) void bscan_kernel(
    const int* __restrict__ bhist, int* __restrict__ brow,
    int* __restrict__ gcur) {
    int g = threadIdx.x >> 6, lane = threadIdx.x & 63;
    int v = bhist[g * KMAX + lane];
    int inc = v;
    #pragma unroll
    for (int off = 1; off < 64; off <<= 1) {
        int u = __shfl_up(inc, off);
        if (lane >= off) inc += u;
    }
    int ex = inc - v;
    brow[g * (KMAX + 1) + lane] = ex;
    if (lane == 63) brow[g * (KMAX + 1) + KMAX] = inc;
    gcur[g * KMAX + lane] = ex;
}

// LDS radix partition: per 4096-edge block, sort by bucket in LDS, reserve one
// contiguous global run per bucket, stream out coalesced.
__global__ __launch_bounds__(256) void partition_kernel(
    const int* __restrict__ src, const int* __restrict__ dst,
    const int* __restrict__ sim_src, const int* __restrict__ sim_dst,
    int* __restrict__ gcur, unsigned* __restrict__ staged,
    int E, int Es, int nbo) {
    int b = blockIdx.x;
    const int* S; const int* D; int Eg; int goff; unsigned* stg;
    if (b < nbo) { S = src; D = dst; Eg = E; goff = 0; stg = staged; }
    else { b -= nbo; S = sim_src; D = sim_dst; Eg = Es; goff = KMAX; stg = staged + E; }
    int e0 = b * PCHUNK;
    int cnt_blk = Eg - e0; if (cnt_blk > PCHUNK) cnt_blk = PCHUNK;
    __shared__ int hist[KMAX], basep[KMAX], cur[KMAX], gbase[KMAX];
    __shared__ unsigned srt[PCHUNK];
    int tid = threadIdx.x;
    if (tid < KMAX) hist[tid] = 0;
    __syncthreads();
    unsigned full[PVPT];
    #pragma unroll
    for (int i = 0; i < PVPT; ++i) {
        int idx = i * 256 + tid;
        if (idx < cnt_blk) {
            int e = e0 + idx;
            int d = D[e];
            unsigned bk = (unsigned)d >> KB_BITS;
            full[i] = (bk << 26) | ((unsigned)S[e] << KB_BITS) |
                      (unsigned)(d & ((1 << KB_BITS) - 1));
            atomicAdd(&hist[bk], 1);
        } else full[i] = 0xFFFFFFFFu;
    }
    __syncthreads();
    if (tid < 64) {
        int v = hist[tid];
        int inc = v;
        #pragma unroll
        for (int off = 1; off < 64; off <<= 1) {
            int u = __shfl_up(inc, off);
            if (tid >= off) inc += u;
        }
        int ex = inc - v;
        basep[tid] = ex;
        cur[tid] = ex;
        gbase[tid] = v ? atomicAdd(&gcur[goff + tid], v) : 0;
    }
    __syncthreads();
    #pragma unroll
    for (int i = 0; i < PVPT; ++i) {
        unsigned f = full[i];
        if (f != 0xFFFFFFFFu) {
            unsigned bk = f >> 26;
            int slot = atomicAdd(&cur[bk], 1);
            srt[slot] = f;
        }
    }
    __syncthreads();
    for (int slot = tid; slot < cnt_blk; slot += 256) {
        unsigned f = srt[slot];
        unsigned bk = f >> 26;
        int gpos = gbase[bk] + (slot - basep[bk]);
        stg[gpos] = f & 0x3FFFFFFu;      // (src<<10)|dlow
    }
}

// One block per bucket: per-node counts -> row/pend/dinv, pad-fill (src=N),
// then scatter u16 esrc inside the bucket's private padded window.
__global__ __launch_bounds__(512) void place_kernel(
    const unsigned* __restrict__ staged, const int* __restrict__ brow,
    int* __restrict__ row_o, int* __restrict__ row_s,
    int* __restrict__ pend_o, int* __restrict__ pend_s,
    unsigned short* __restrict__ esrc_o, unsigned short* __restrict__ esrc_s,
    float* __restrict__ dinv, int N, int K, int E, int pad) {
    int b = blockIdx.x;
    const unsigned* stg; const int* br; int* row; int* pend;
    unsigned short* esrc; float* dv;
    if (b < K) { stg = staged; br = brow; row = row_o; pend = pend_o; esrc = esrc_o; dv = dinv; }
    else { b -= K; stg = staged + E; br = brow + (KMAX + 1); row = row_s; pend = pend_s; esrc = esrc_s; dv = dinv + N; }
    int node0 = b << KB_BITS;
    int nn = N - node0; if (nn > (1 << KB_BITS)) nn = (1 << KB_BITS);
    int seg0 = br[b], seg1 = br[b + 1];
    int base = pad ? (seg0 + b * PADMAX) : seg0;
    __shared__ int ncnt[1 << KB_BITS];
    __shared__ int wsum[8];
    int tid = threadIdx.x;
    for (int i = tid; i < (1 << KB_BITS); i += 512) ncnt[i] = 0;
    __syncthreads();
    for (int j = seg0 + tid; j < seg1; j += 512)
        atomicAdd(&ncnt[stg[j] & ((1 << KB_BITS) - 1)], 1);
    __syncthreads();
    int i0 = tid * 2;
    int v0 = ncnt[i0], v1 = ncnt[i0 + 1];
    int p0 = pad ? ((v0 + 7) & ~7) : v0;
    int p1 = pad ? ((v1 + 7) & ~7) : v1;
    int s = p0 + p1;
    int inc = s;
    #pragma unroll
    for (int off = 1; off < 64; off <<= 1) {
        int u = __shfl_up(inc, off);
        if ((tid & 63) >= off) inc += u;
    }
    if ((tid & 63) == 63) wsum[tid >> 6] = inc;
    __syncthreads();
    int wo = 0;
    for (int w = 0; w < (tid >> 6); ++w) wo += wsum[w];
    int ex = base + wo + inc - s;
    if (i0 < nn) {
        row[node0 + i0] = ex;
        pend[node0 + i0] = ex + p0;
        dv[node0 + i0] = rsqrtf((float)(v0 > 1 ? v0 : 1));
        for (int q = ex + v0; q < ex + p0; ++q) esrc[q] = (unsigned short)N;
    }
    if (i0 + 1 < nn) {
        int ex2 = ex + p0;
        row[node0 + i0 + 1] = ex2;
        pend[node0 + i0 + 1] = ex2 + p1;
        dv[node0 + i0 + 1] = rsqrtf((float)(v1 > 1 ? v1 : 1));
        for (int q = ex2 + v1; q < ex2 + p1; ++q) esrc[q] = (unsigned short)N;
    }
    if (!pad && b == K - 1 && tid == 0) row[N] = br[K];
    __syncthreads();
    ncnt[i0] = ex;
    ncnt[i0 + 1] = ex + p0;
    __syncthreads();
    for (int j = seg0 + tid; j < seg1; j += 512) {
        unsigned f = stg[j];
        int pos = atomicAdd(&ncnt[f & ((1 << KB_BITS) - 1)], 1);
        esrc[pos] = (unsigned short)(f >> KB_BITS);
    }
}

// Fold Wm1 (384x64) -> w1f (256x64): rows 192..255 = sum of the 3 sim blocks.
// Block 0 also zeroes bhist (replaces the memset dispatch).
__global__ __launch_bounds__(256) void fold_kernel(
    const float* __restrict__ Wm1, float* __restrict__ w1f,
    int* __restrict__ bhist) {
    int i = blockIdx.x * 256 + threadIdx.x;
    if (blockIdx.x == 0 && threadIdx.x < 2 * KMAX) bhist[threadIdx.x] = 0;
    if (i >= 256 * 64) return;
    int k = i >> 6, j = i & 63;
    float v = Wm1[k * 64 + j];
    if (k >= 192) v += Wm1[(k + 64) * 64 + j] + Wm1[(k + 128) * 64 + j];
    w1f[i] = v;
}

// Both input GEMMs in one launch: block < nbh -> ortho, else sim.
// f16path: writes h16 = relu*dinv (premul) and, if use8, fp8 shadow h8.
__global__ __launch_bounds__(256) void in_gemm2_kernel(
    const float* __restrict__ x, const float* __restrict__ sim_x,
    const float* __restrict__ W1_o, const float* __restrict__ b1_o,
    const float* __restrict__ W1_s, const float* __restrict__ b1_s,
    float* __restrict__ hall, __half* __restrict__ h16_o, __half* __restrict__ h16_s,
    __half* __restrict__ g16_o, __half* __restrict__ g16_s,
    unsigned char* __restrict__ h8_o, unsigned char* __restrict__ h8_s,
    unsigned char* __restrict__ g8_o, unsigned char* __restrict__ g8_s,
    const float* __restrict__ dinv, int n, int nbh, int f16path, int pad, int use8) {
    int bb = blockIdx.x;
    const float* xin; const float* W; const float* b; __half* h16;
    unsigned char* h8; const float* dinvv; int off;
    if (bb < nbh) { xin = x; W = W1_o; b = b1_o; h16 = h16_o; h8 = h8_o; dinvv = dinv; off = 0; }
    else { bb -= nbh; xin = sim_x; W = W1_s; b = b1_s; h16 = h16_s; h8 = h8_s; dinvv = dinv + n; off = 192; }
    if (pad && threadIdx.x < 64) {       // zero rows for padded gathers
        if (blockIdx.x == 0) {
            h16_o[(long)n * 64 + threadIdx.x] = __float2half_rn(0.f);
            g16_o[(long)n * 64 + threadIdx.x] = __float2half_rn(0.f);
            if (use8) { h8_o[(long)n * 64 + threadIdx.x] = 0; g8_o[(long)n * 64 + threadIdx.x] = 0; }
        } else if (blockIdx.x == nbh) {
            h16_s[(long)n * 64 + threadIdx.x] = __float2half_rn(0.f);
            g16_s[(long)n * 64 + threadIdx.x] = __float2half_rn(0.f);
            if (use8) { h8_s[(long)n * 64 + threadIdx.x] = 0; g8_s[(long)n * 64 + threadIdx.x] = 0; }
        }
    }
    __shared__ float xs[64][132];
    __shared__ float Wf[128][68];
    int tid = threadIdx.x;
    int node0 = bb * 64;
    const float4* wsrc = (const float4*)W;
    for (int i = tid; i < 2048; i += 256)
        *(float4*)&Wf[i >> 4][(i & 15) * 4] = wsrc[i];
    const float4* xsrc = (const float4*)xin;
    for (int i = tid; i < 2048; i += 256) {
        int nl = i >> 5, c = i & 31;
        int node = node0 + nl;
        float4 v = make_float4(0.f, 0.f, 0.f, 0.f);
        if (node < n) v = xsrc[(long)node * 32 + c];
        *(float4*)&xs[nl][c * 4] = v;
    }
    __syncthreads();
    int tx = tid & 15, ty = tid >> 4;
    float acc[4][4] = {};
    #pragma unroll 2
    for (int k = 0; k < 128; k += 4) {
        float4 a[4], bbv[4];
        #pragma unroll
        for (int i = 0; i < 4; ++i) a[i] = *(const float4*)&xs[ty * 4 + i][k];
        #pragma unroll
        for (int j = 0; j < 4; ++j) bbv[j] = *(const float4*)&Wf[k + j][tx * 4];
        #pragma unroll
        for (int i = 0; i < 4; ++i) {
            acc[i][0] = fmaf(a[i].x, bbv[0].x, acc[i][0]);
            acc[i][1] = fmaf(a[i].x, bbv[0].y, acc[i][1]);
            acc[i][2] = fmaf(a[i].x, bbv[0].z, acc[i][2]);
            acc[i][3] = fmaf(a[i].x, bbv[0].w, acc[i][3]);
            acc[i][0] = fmaf(a[i].y, bbv[1].x, acc[i][0]);
            acc[i][1] = fmaf(a[i].y, bbv[1].y, acc[i][1]);
            acc[i][2] = fmaf(a[i].y, bbv[1].z, acc[i][2]);
            acc[i][3] = fmaf(a[i].y, bbv[1].w, acc[i][3]);
            acc[i][0] = fmaf(a[i].z, bbv[2].x, acc[i][0]);
            acc[i][1] = fmaf(a[i].z, bbv[2].y, acc[i][1]);
            acc[i][2] = fmaf(a[i].z, bbv[2].z, acc[i][2]);
            acc[i][3] = fmaf(a[i].z, bbv[2].w, acc[i][3]);
            acc[i][0] = fmaf(a[i].w, bbv[3].x, acc[i][0]);
            acc[i][1] = fmaf(a[i].w, bbv[3].y, acc[i][1]);
            acc[i][2] = fmaf(a[i].w, bbv[3].z, acc[i][2]);
            acc[i][3] = fmaf(a[i].w, bbv[3].w, acc[i][3]);
        }
    }
    float4 bias = *(const float4*)&b[tx * 4];
    #pragma unroll
    for (int i = 0; i < 4; ++i) {
        int node = node0 + ty * 4 + i;
        if (node >= n) break;
        float4 r;
        r.x = fmaxf(acc[i][0] + bias.x, 0.0f);
        r.y = fmaxf(acc[i][1] + bias.y, 0.0f);
        r.z = fmaxf(acc[i][2] + bias.z, 0.0f);
        r.w = fmaxf(acc[i][3] + bias.w, 0.0f);
        if (f16path) {
            float dvn = dinvv[node];
            float v0 = r.x * dvn, v1 = r.y * dvn, v2 = r.z * dvn, v3 = r.w * dvn;
            __half hh[4];
            hh[0] = __float2half_rn(v0);
            hh[1] = __float2half_rn(v1);
            hh[2] = __float2half_rn(v2);
            hh[3] = __float2half_rn(v3);
            *(float2*)&h16[(long)node * 64 + tx * 4] = *(float2*)hh;
            if (use8) {
                uchar4 q;
                q.x = to8(v0); q.y = to8(v1); q.z = to8(v2); q.w = to8(v3);
                *(uchar4*)&h8[(long)node * 64 + tx * 4] = q;
            }
        } else {
            *(float4*)&hall[(long)node * 384 + off + tx * 4] = r;
        }
    }
}

// Hop 1: 1 node/wave, uniform 16/8 batches. Gathers fp8 h8 (use8) or fp16 h16.
// Own-row f0 always fp16. Writes g16 (fp16) + g8 (fp8 shadow, use8).
__global__ __launch_bounds__(256) void hop1_kernel(
    const int* __restrict__ row_o, const int* __restrict__ pend_o,
    const unsigned short* __restrict__ esrc_o, const float* __restrict__ dinv_o,
    const int* __restrict__ row_s, const int* __restrict__ pend_s,
    const unsigned short* __restrict__ esrc_s, const float* __restrict__ dinv_s,
    const __half* __restrict__ h16_o, const __half* __restrict__ h16_s,
    __half* __restrict__ g16_o, __half* __restrict__ g16_s,
    const unsigned char* __restrict__ h8_o, const unsigned char* __restrict__ h8_s,
    unsigned char* __restrict__ g8_o, unsigned char* __restrict__ g8_s,
    int n, int nb, int use8) {
    int b = blockIdx.x;
    const int* row; const int* pend; const unsigned short* esrc;
    const float* dinv; const __half* h16; __half* g16;
    const unsigned char* h8; unsigned char* g8;
    if (b < nb) { row = row_o; pend = pend_o; esrc = esrc_o; dinv = dinv_o;
                  h16 = h16_o; g16 = g16_o; h8 = h8_o; g8 = g8_o; }
    else { b -= nb; row = row_s; pend = pend_s; esrc = esrc_s; dinv = dinv_s;
           h16 = h16_s; g16 = g16_s; h8 = h8_s; g8 = g8_s; }
    int d = b * 4 + (threadIdx.x >> 6);
    if (d >= n) return;
    int lane = threadIdx.x & 63;
    int p = row[d], end = pend[d];
    float dd = dinv[d];
    float h16v = __half2float(h16[((unsigned)d << 6) | lane]);
    float a0 = 0.f, a1 = 0.f, a2 = 0.f, a3 = 0.f;
    if (use8) {
        for (; p + 16 <= end; p += 16) {
            unsigned ss[16];
            #pragma unroll
            for (int i = 0; i < 16; ++i) ss[i] = esrc[p + i];
            #pragma unroll
            for (int i = 0; i < 16; i += 4) {
                a0 += cv8(h8[(ss[i] << 6) | lane]);
                a1 += cv8(h8[(ss[i + 1] << 6) | lane]);
                a2 += cv8(h8[(ss[i + 2] << 6) | lane]);
                a3 += cv8(h8[(ss[i + 3] << 6) | lane]);
            }
        }
        if (p + 8 <= end) {
            unsigned ss[8];
            #pragma unroll
            for (int i = 0; i < 8; ++i) ss[i] = esrc[p + i];
            #pragma unroll
            for (int i = 0; i < 8; i += 4) {
                a0 += cv8(h8[(ss[i] << 6) | lane]);
                a1 += cv8(h8[(ss[i + 1] << 6) | lane]);
                a2 += cv8(h8[(ss[i + 2] << 6) | lane]);
                a3 += cv8(h8[(ss[i + 3] << 6) | lane]);
            }
            p += 8;
        }
        for (; p < end; ++p)
            a0 += cv8(h8[((unsigned)esrc[p] << 6) | lane]);
    } else {
        for (; p + 16 <= end; p += 16) {
            unsigned ss[16];
            #pragma unroll
            for (int i = 0; i < 16; ++i) ss[i] = esrc[p + i];
            #pragma unroll
            for (int i = 0; i < 16; i += 4) {
                a0 += __half2float(h16[(ss[i] << 6) | lane]);
                a1 += __half2float(h16[(ss[i + 1] << 6) | lane]);
                a2 += __half2float(h16[(ss[i + 2] << 6) | lane]);
                a3 += __half2float(h16[(ss[i + 3] << 6) | lane]);
            }
        }
        if (p + 8 <= end) {
            unsigned ss[8];
            #pragma unroll
            for (int i = 0; i < 8; ++i) ss[i] = esrc[p + i];
            #pragma unroll
            for (int i = 0; i < 8; i += 4) {
                a0 += __half2float(h16[(ss[i] << 6) | lane]);
                a1 += __half2float(h16[(ss[i + 1] << 6) | lane]);
                a2 += __half2float(h16[(ss[i + 2] << 6) | lane]);
                a3 += __half2float(h16[(ss[i + 3] << 6) | lane]);
            }
            p += 8;
        }
        for (; p + 4 <= end; p += 4) {
            unsigned s0 = esrc[p], s1 = esrc[p + 1], s2 = esrc[p + 2], s3 = esrc[p + 3];
            a0 += __half2float(h16[(s0 << 6) | lane]);
            a1 += __half2float(h16[(s1 << 6) | lane]);
            a2 += __half2float(h16[(s2 << 6) | lane]);
            a3 += __half2float(h16[(s3 << 6) | lane]);
        }
        for (; p < end; ++p)
            a0 += __half2float(h16[((unsigned)esrc[p] << 6) | lane]);
    }
    float acc = (a0 + a1) + (a2 + a3);
    float val = h16v - acc * dd * dd;     // = f1*dinv
    g16[((unsigned)d << 6) | lane] = __float2half_rn(val);
    if (use8) g8[((unsigned)d << 6) | lane] = to8(val);
}

// Hop 2 + theta-combine: gathers fp8 g8 (use8) or fp16 g16; own rows fp16.
__global__ __launch_bounds__(256) void hop2_kernel(
    const int* __restrict__ row_o, const int* __restrict__ pend_o,
    const unsigned short* __restrict__ esrc_o, const float* __restrict__ dinv_o,
    const int* __restrict__ row_s, const int* __restrict__ pend_s,
    const unsigned short* __restrict__ esrc_s, const float* __restrict__ dinv_s,
    const __half* __restrict__ h16_o, const __half* __restrict__ h16_s,
    const __half* __restrict__ g16_o, const __half* __restrict__ g16_s,
    const unsigned char* __restrict__ g8_o, const unsigned char* __restrict__ g8_s,
    float* __restrict__ hall, int n, int nb, int use8) {
    int b = blockIdx.x;
    int g = (b < nb) ? 0 : 1;
    const int* row; const int* pend; const unsigned short* esrc;
    const float* dinv; const __half* h16; const __half* g16;
    const unsigned char* g8;
    if (g == 0) { row = row_o; pend = pend_o; esrc = esrc_o; dinv = dinv_o;
                  h16 = h16_o; g16 = g16_o; g8 = g8_o; }
    else { b -= nb; row = row_s; pend = pend_s; esrc = esrc_s; dinv = dinv_s;
           h16 = h16_s; g16 = g16_s; g8 = g8_s; }
    int d = b * 4 + (threadIdx.x >> 6);
    if (d >= n) return;
    int lane = threadIdx.x & 63;
    int p = row[d], end = pend[d];
    float dd = dinv[d];
    float sq = 1.0f / dd;                 // = sqrt(clamped degree)
    float f0 = __half2float(h16[((unsigned)d << 6) | lane]) * sq;
    float f1 = __half2float(g16[((unsigned)d << 6) | lane]) * sq;
    float a0 = 0.f, a1 = 0.f, a2 = 0.f, a3 = 0.f;
    if (use8) {
        for (; p + 16 <= end; p += 16) {
            unsigned ss[16];
            #pragma unroll
            for (int i = 0; i < 16; ++i) ss[i] = esrc[p + i];
            #pragma unroll
            for (int i = 0; i < 16; i += 4) {
                a0 += cv8(g8[(ss[i] << 6) | lane]);
                a1 += cv8(g8[(ss[i + 1] << 6) | lane]);
                a2 += cv8(g8[(ss[i + 2] << 6) | lane]);
                a3 += cv8(g8[(ss[i + 3] << 6) | lane]);
            }
        }
        if (p + 8 <= end) {
            unsigned ss[8];
            #pragma unroll
            for (int i = 0; i < 8; ++i) ss[i] = esrc[p + i];
            #pragma unroll
            for (int i = 0; i < 8; i += 4) {
                a0 += cv8(g8[(ss[i] << 6) | lane]);
                a1 += cv8(g8[(ss[i + 1] << 6) | lane]);
                a2 += cv8(g8[(ss[i + 2] << 6) | lane]);
                a3 += cv8(g8[(ss[i + 3] << 6) | lane]);
            }
            p += 8;
        }
        for (; p < end; ++p)
            a0 += cv8(g8[((unsigned)esrc[p] << 6) | lane]);
    } else {
        for (; p + 16 <= end; p += 16) {
            unsigned ss[16];
            #pragma unroll
            for (int i = 0; i < 16; ++i) ss[i] = esrc[p + i];
            #pragma unroll
            for (int i = 0; i < 16; i += 4) {
                a0 += __half2float(g16[(ss[i] << 6) | lane]);
                a1 += __half2float(g16[(ss[i + 1] << 6) | lane]);
                a2 += __half2float(g16[(ss[i + 2] << 6) | lane]);
                a3 += __half2float(g16[(ss[i + 3] << 6) | lane]);
            }
        }
        if (p + 8 <= end) {
            unsigned ss[8];
            #pragma unroll
            for (int i = 0; i < 8; ++i) ss[i] = esrc[p + i];
            #pragma unroll
            for (int i = 0; i < 8; i += 4) {
                a0 += __half2float(g16[(ss[i] << 6) | lane]);
                a1 += __half2float(g16[(ss[i + 1] << 6) | lane]);
                a2 += __half2float(g16[(ss[i + 2] << 6) | lane]);
                a3 += __half2float(g16[(ss[i + 3] << 6) | lane]);
            }
            p += 8;
        }
        for (; p + 4 <= end; p += 4) {
            unsigned s0 = esrc[p], s1 = esrc[p + 1], s2 = esrc[p + 2], s3 = esrc[p + 3];
            a0 += __half2float(g16[(s0 << 6) | lane]);
            a1 += __half2float(g16[(s1 << 6) | lane]);
            a2 += __half2float(g16[(s2 << 6) | lane]);
            a3 += __half2float(g16[(s3 << 6) | lane]);
        }
        for (; p < end; ++p)
            a0 += __half2float(g16[((unsigned)esrc[p] << 6) | lane]);
    }
    float acc = (a0 + a1) + (a2 + a3);
    float f2 = f1 - acc * dd;
    long ob = (long)d * 384 + lane;
    if (g == 0) {
        hall[ob]       = 3.0f * f0 - 3.0f * f1 + 0.75f * f2;
        hall[ob + 64]  = 3.0f * f1 - 1.5f * f2;
        hall[ob + 128] = 0.75f * f2;
    } else {
        float ss = 4.0f * (f0 + f1 + f2);
        hall[ob + 192] = ss; hall[ob + 256] = ss; hall[ob + 320] = ss;
    }
}

// ---------- fallback path (ws too small for fp16 shadows) ----------
__global__ __launch_bounds__(256) void gather2_kernel(
    const int* __restrict__ row_o, const unsigned short* __restrict__ esrc_o,
    const float* __restrict__ dinv_o,
    const int* __restrict__ row_s, const unsigned short* __restrict__ esrc_s,
    const float* __restrict__ dinv_s,
    float* __restrict__ hall, int in_off_o, int in_off_s, int n, int nb) {
    int b = blockIdx.x;
    const int* row; const unsigned short* esrc; const float* dinv; int in_off;
    if (b < nb) { row = row_o; esrc = esrc_o; dinv = dinv_o; in_off = in_off_o; }
    else { b -= nb; row = row_s; esrc = esrc_s; dinv = dinv_s; in_off = in_off_s; }
    int d = b * 4 + (threadIdx.x >> 6);
    if (d >= n) return;
    int lane = threadIdx.x & 63;
    int p = row[d], end = row[d + 1];
    const float* fin = hall + in_off;
    float a0 = 0.f, a1 = 0.f, a2 = 0.f, a3 = 0.f;
    for (; p + 4 <= end; p += 4) {
        int s0 = esrc[p], s1 = esrc[p + 1], s2 = esrc[p + 2], s3 = esrc[p + 3];
        a0 = fmaf(fin[(long)s0 * 384 + lane], dinv[s0], a0);
        a1 = fmaf(fin[(long)s1 * 384 + lane], dinv[s1], a1);
        a2 = fmaf(fin[(long)s2 * 384 + lane], dinv[s2], a2);
        a3 = fmaf(fin[(long)s3 * 384 + lane], dinv[s3], a3);
    }
    for (; p < end; ++p) {
        int s = esrc[p];
        a0 = fmaf(fin[(long)s * 384 + lane], dinv[s], a0);
    }
    float acc = (a0 + a1) + (a2 + a3);
    long ob = (long)d * 384 + lane;
    hall[ob + in_off + 64] = fin[ob] - acc * dinv[d];
}

__global__ __launch_bounds__(256) void combine_kernel(float* __restrict__ h, int nf) {
    int i = blockIdx.x * 256 + threadIdx.x;
    if (i >= nf) return;
    long ob = (long)(i >> 6) * 384 + (i & 63);
    float f0v = h[ob], f1v = h[ob + 64], f2v = h[ob + 128];
    h[ob]       = 3.0f * f0v - 3.0f * f1v + 0.75f * f2v;
    h[ob + 64]  = 3.0f * f1v - 1.5f * f2v;
    h[ob + 128] = 0.75f * f2v;
    float ss = 4.0f * (h[ob + 192] + h[ob + 256] + h[ob + 320]);
    h[ob + 192] = ss; h[ob + 256] = ss; h[ob + 320] = ss;
}
// -------------------------------------------------------------------

// logits = relu(h_all @ Wm1f + bm1) @ Wm2 + bm2. K=256 (sim slots folded).
__global__ __launch_bounds__(256) void mlp_kernel(
    const float* __restrict__ hall, const float* __restrict__ w1f,
    const float* __restrict__ bm1, const float* __restrict__ Wm2,
    const float* __restrict__ bm2, float* __restrict__ logits, int n) {
    __shared__ float xs[64][132];
    __shared__ float Wf[128][68];
    int tid = threadIdx.x;
    int node0 = blockIdx.x * 64;
    int tx = tid & 15, ty = tid >> 4;
    float acc[4][4] = {};
    const float4* wsrc = (const float4*)w1f;
    const float4* hsrc = (const float4*)hall;
    for (int c = 0; c < 2; ++c) {
        __syncthreads();
        for (int i = tid; i < 2048; i += 256)
            *(float4*)&Wf[i >> 4][(i & 15) * 4] = wsrc[c * 2048 + i];
        for (int i = tid; i < 2048; i += 256) {
            int nl = i >> 5, cc = i & 31;
            int node = node0 + nl;
            float4 v = make_float4(0.f, 0.f, 0.f, 0.f);
            if (node < n) v = hsrc[(long)node * 96 + c * 32 + cc];
            *(float4*)&xs[nl][cc * 4] = v;
        }
        __syncthreads();
        #pragma unroll 2
        for (int k = 0; k < 128; k += 4) {
            float4 a[4], bb[4];
            #pragma unroll
            for (int i = 0; i < 4; ++i) a[i] = *(const float4*)&xs[ty * 4 + i][k];
            #pragma unroll
            for (int j = 0; j < 4; ++j) bb[j] = *(const float4*)&Wf[k + j][tx * 4];
            #pragma unroll
            for (int i = 0; i < 4; ++i) {
                acc[i][0] = fmaf(a[i].x, bb[0].x, acc[i][0]);
                acc[i][1] = fmaf(a[i].x, bb[0].y, acc[i][1]);
                acc[i][2] = fmaf(a[i].x, bb[0].z, acc[i][2]);
                acc[i][3] = fmaf(a[i].x, bb[0].w, acc[i][3]);
                acc[i][0] = fmaf(a[i].y, bb[1].x, acc[i][0]);
                acc[i][1] = fmaf(a[i].y, bb[1].y, acc[i][1]);
                acc[i][2] = fmaf(a[i].y, bb[1].z, acc[i][2]);
                acc[i][3] = fmaf(a[i].y, bb[1].w, acc[i][3]);
                acc[i][0] = fmaf(a[i].z, bb[2].x, acc[i][0]);
                acc[i][1] = fmaf(a[i].z, bb[2].y, acc[i][1]);
                acc[i][2] = fmaf(a[i].z, bb[2].z, acc[i][2]);
                acc[i][3] = fmaf(a[i].z, bb[2].w, acc[i][3]);
                acc[i][0] = fmaf(a[i].w, bb[3].x, acc[i][0]);
                acc[i][1] = fmaf(a[i].w, bb[3].y, acc[i][1]);
                acc[i][2] = fmaf(a[i].w, bb[3].z, acc[i][2]);
                acc[i][3] = fmaf(a[i].w, bb[3].w, acc[i][3]);
            }
        }
    }
    __syncthreads();
    float4 bias = *(const float4*)&bm1[tx * 4];
    #pragma unroll
    for (int i = 0; i < 4; ++i) {
        xs[ty * 4 + i][tx * 4 + 0] = fmaxf(acc[i][0] + bias.x, 0.0f);
        xs[ty * 4 + i][tx * 4 + 1] = fmaxf(acc[i][1] + bias.y, 0.0f);
        xs[ty * 4 + i][tx * 4 + 2] = fmaxf(acc[i][2] + bias.z, 0.0f);
        xs[ty * 4 + i][tx * 4 + 3] = fmaxf(acc[i][3] + bias.w, 0.0f);
    }
    __syncthreads();
    if (tid < 128) {
        int nl = tid >> 1, o = tid & 1;
        int node = node0 + nl;
        if (node < n) {
            float p = bm2[o];
            #pragma unroll 8
            for (int k = 0; k < 64; ++k) p = fmaf(xs[nl][k], Wm2[k * 2 + o], p);
            logits[(long)node * 2 + o] = p;
        }
    }
}

extern "C" void kernel_launch(void* const* d_in, const int* in_sizes, int n_in,
                              void* d_out, int out_size, void* d_ws, size_t ws_size,
                              hipStream_t stream) {
    const float* x     = (const float*)d_in[0];
    const float* sim_x = (const float*)d_in[1];
    const int* src     = (const int*)d_in[2];
    const int* dst     = (const int*)d_in[3];
    const int* sim_src = (const int*)d_in[4];
    const int* sim_dst = (const int*)d_in[5];
    const float* W1_o = (const float*)d_in[6];
    const float* b1_o = (const float*)d_in[7];
    const float* W1_s = (const float*)d_in[8];
    const float* b1_s = (const float*)d_in[9];
    const float* Wm1  = (const float*)d_in[10];
    const float* bm1  = (const float*)d_in[11];
    const float* Wm2  = (const float*)d_in[12];
    const float* bm2  = (const float*)d_in[13];

    const int N  = in_sizes[0] / 128;  // 50000 (must be <= 65535 for u16 path)
    const int E  = in_sizes[2];        // 800000
    const int Es = in_sizes[4];
    const int NF = N * 64;
    const int K  = (N + (1 << KB_BITS) - 1) >> KB_BITS;  // 1024-node buckets

    float* hall = (float*)d_out;                 // N x 384
    float* lgt  = hall + (long)N * 384;          // N x 2
    float* dinv = lgt;                           // [dinv_o N | dinv_s N] until MLP
    float* dinv_o = dinv;
    float* dinv_s = dinv + N;

    // ---- workspace layout: tiers A2 (pad+fp8) > A (pad) > B (unpadded) > C ----
    int* row_o  = (int*)d_ws;            // N+1
    int* row_s  = row_o + (N + 1);       // N+1
    int* pend_o = row_s + (N + 1);       // N
    int* pend_s = pend_o + N;            // N
    unsigned short* esrc_o = (unsigned short*)(pend_s + N);
    long esz_pad   = ((long)E + (long)K * PADMAX + 1) & ~1L;   // u16 count
    long esz_pad_s = ((long)Es + (long)K * PADMAX + 1) & ~1L;
    long esz_b     = ((long)E + 1) & ~1L;
    long esz_b_s   = ((long)Es + 1) & ~1L;

    unsigned short* esrc_sA = esrc_o + esz_pad;
    int* bhistA = (int*)(esrc_sA + esz_pad_s);
    unsigned short* esrc_sB = esrc_o + esz_b;
    int* bhistB = (int*)(esrc_sB + esz_b_s);

    // tail = f16 arrays; tail8 = + fp8 arrays
    auto layout_tail = [&](int* bh, bool with8) -> char* {
        int* br = bh + 2 * KMAX;
        int* gc = br + 2 * (KMAX + 1);
        float* wf = (float*)(gc + 2 * KMAX);
        __half* h = (__half*)(wf + 256 * 64);
        char* t = (char*)(h + 4 * (long)(N + 1) * 64);
        if (with8) t += 4 * (long)(N + 1) * 64;      // 4 fp8 arrays, 1B each
        return t;
    };
    bool u16ok = N <= 65535;
    bool padA2 = u16ok && (size_t)(layout_tail(bhistA, true)  - (char*)d_ws) <= ws_size;
    bool padA  = padA2 ||
        (u16ok && (size_t)(layout_tail(bhistA, false) - (char*)d_ws) <= ws_size);
    unsigned short* esrc_s = padA ? esrc_sA : esrc_sB;
    int* bhist  = padA ? bhistA : bhistB;
    int* brow   = bhist + 2 * KMAX;
    int* gcur   = brow + 2 * (KMAX + 1);
    float* w1f  = (float*)(gcur + 2 * KMAX);
    __half* h16_o = (__half*)(w1f + 256 * 64);   // (N+1)*64 halves each
    __half* h16_s = h16_o + (long)(N + 1) * 64;
    __half* g16_o = h16_s + (long)(N + 1) * 64;
    __half* g16_s = g16_o + (long)(N + 1) * 64;
    unsigned char* h8_o = (unsigned char*)(g16_s + (long)(N + 1) * 64);
    unsigned char* h8_s = h8_o + (long)(N + 1) * 64;
    unsigned char* g8_o = h8_s + (long)(N + 1) * 64;
    unsigned char* g8_s = g8_o + (long)(N + 1) * 64;
    bool f16path = u16ok && (padA ||
        ((size_t)(layout_tail(bhistB, false) - (char*)d_ws) <= ws_size));
    int pad = padA ? 1 : 0;
    int use8 = padA2 ? 1 : 0;
    // staged[E+Es] aliases h16 region: consumed by place BEFORE in_gemm writes h16.
    unsigned* staged = (unsigned*)h16_o;
    const int* pend_o_use = pad ? pend_o : (row_o + 1);
    const int* pend_s_use = pad ? pend_s : (row_s + 1);

    int nb4  = (N + 3) / 4;
    int nb64 = (N + 63) / 64;
    int nfb  = (NF + 255) / 256;
    int nbo  = (E + PCHUNK - 1) / PCHUNK;
    int nbs  = (Es + PCHUNK - 1) / PCHUNK;

    // ---- CSR build: fold(+bhist zero) -> hist -> bases -> partition -> place ----
    fold_kernel<<<64, 256, 0, stream>>>(Wm1, w1f, bhist);
    bhist_kernel<<<256, 256, 0, stream>>>(dst, sim_dst, bhist, E, Es);
    bscan_kernel<<<1, 128, 0, stream>>>(bhist, brow, gcur);
    partition_kernel<<<nbo + nbs, 256, 0, stream>>>(src, dst, sim_src, sim_dst,
                                                    gcur, staged, E, Es, nbo);
    place_kernel<<<2 * K, 512, 0, stream>>>(staged, brow, row_o, row_s,
                                            pend_o, pend_s, esrc_o, esrc_s,
                                            dinv, N, K, E, pad);

    // ---- input GEMMs (one launch, both graphs; zeroes pad rows) ----
    in_gemm2_kernel<<<2 * nb64, 256, 0, stream>>>(x, sim_x, W1_o, b1_o, W1_s, b1_s,
                                                  hall, h16_o, h16_s, g16_o, g16_s,
                                                  h8_o, h8_s, g8_o, g8_s,
                                                  dinv, N, nb64, f16path ? 1 : 0,
                                                  pad, use8);

    if (f16path) {
        hop1_kernel<<<2 * nb4, 256, 0, stream>>>(row_o, pend_o_use, esrc_o, dinv_o,
                                                 row_s, pend_s_use, esrc_s, dinv_s,
                                                 h16_o, h16_s, g16_o, g16_s,
                                                 h8_o, h8_s, g8_o, g8_s,
                                                 N, nb4, use8);
        hop2_kernel<<<2 * nb4, 256, 0, stream>>>(row_o, pend_o_use, esrc_o, dinv_o,
                                                 row_s, pend_s_use, esrc_s, dinv_s,
                                                 h16_o, h16_s, g16_o, g16_s,
                                                 g8_o, g8_s, hall, N, nb4, use8);
    } else {
        gather2_kernel<<<2 * nb4, 256, 0, stream>>>(row_o, esrc_o, dinv_o,
                                                    row_s, esrc_s, dinv_s,
                                                    hall, 0, 192, N, nb4);
        gather2_kernel<<<2 * nb4, 256, 0, stream>>>(row_o, esrc_o, dinv_o,
                                                    row_s, esrc_s, dinv_s,
                                                    hall, 64, 256, N, nb4);
        combine_kernel<<<nfb, 256, 0, stream>>>(hall, NF);
    }

    // ---- MLP head (folded K=256; overwrites dinv stash with logits) ----
    mlp_kernel<<<nb64, 256, 0, stream>>>(hall, w1f, bm1, Wm2, bm2, lgt, N);
}